// Round 3
// baseline (640.797 us; speedup 1.0000x reference)
//
#include <hip/hip_runtime.h>

#define Bsz  2048
#define Tlen 512
#define Din  32
#define Hd   64
#define BT   32            // TWO independent 16-batch tiles per block (A and B)
#define HS   72            // h-tile row stride in f16 elems (144B, 16B-aligned reads)
#define BUFE 2048          // f16 elems per h buffer (4096 B); 8 buffers: A=[0..3], B=[4..7]

typedef _Float16 half8 __attribute__((ext_vector_type(8)));
typedef _Float16 half4 __attribute__((ext_vector_type(4)));
typedef float    f32x4 __attribute__((ext_vector_type(4)));

// TRANSPOSED formulation: D = A*B, A = W fragment (rows = gate cols), B = h/x
// fragment (cols = batches). Lane (quad,m) holds batch m, gate cols gc..gc+3
// contiguous -> h writeback is one conflict-free ds_write_b64.
// Two independent batch-tiles share the SAME weight fragments; their step
// bodies interleave inside one barrier region so tile-B work fills tile-A's
// LDS/MFMA latency gaps (and vice versa). One barrier per 2 tile-steps.
#define MFMA(a, b, c) __builtin_amdgcn_mfma_f32_16x16x32_f16((a), (b), (c), 0, 0, 0)

__device__ __forceinline__ half8 load8s(const float* p, float s) {
    half8 r;
#pragma unroll
    for (int j = 0; j < 8; ++j) r[j] = (_Float16)(p[j] * s);
    return r;
}
__device__ __forceinline__ half8 cvt8(float4 a, float4 b) {
    half8 r;
    r[0] = (_Float16)a.x; r[1] = (_Float16)a.y; r[2] = (_Float16)a.z; r[3] = (_Float16)a.w;
    r[4] = (_Float16)b.x; r[5] = (_Float16)b.y; r[6] = (_Float16)b.z; r[7] = (_Float16)b.w;
    return r;
}

// weights pre-scaled by -log2(e) (r,z) and -2*log2(e) (n). With E = 2^(scaled):
//   sigma(raw) = 1/(1+E),  tanh(raw_n) = (1-E_n)/(1+E_n)
// GRU update folds to ONE rcp:  h' = [E_z(1-E_n) + h(1+E_n)] / [(1+E_z)(1+E_n)]
__device__ __forceinline__ void gate_update(const f32x4& gr, const f32x4& gz,
                                            const f32x4& anx, const f32x4& anh,
                                            float hst[4], _Float16* dst, bool wr) {
    half4 pk;
#pragma unroll
    for (int r = 0; r < 4; ++r) {
        float Er = __builtin_amdgcn_exp2f(gr[r]);
        float rr = __builtin_amdgcn_rcpf(1.0f + Er);
        float yy = anx[r] + rr * anh[r];
        float En = __builtin_amdgcn_exp2f(yy);
        float Ez = __builtin_amdgcn_exp2f(gz[r]);
        float num = Ez * (1.0f - En) + hst[r] * (1.0f + En);
        float den = (1.0f + Ez) * (1.0f + En);
        hst[r] = num * __builtin_amdgcn_rcpf(den);
        pk[r] = (_Float16)hst[r];
    }
    if (wr) *(half4*)dst = pk;   // one b64 store, 4 contiguous h cols of batch m
}

__global__ __launch_bounds__(512, 2)
void gru_fused(const float* __restrict__ x,
               const float* __restrict__ Wih0, const float* __restrict__ Whh0,
               const float* __restrict__ bih0, const float* __restrict__ bhh0,
               const float* __restrict__ Wih1, const float* __restrict__ Whh1,
               const float* __restrict__ bih1, const float* __restrict__ bhh1,
               const float* __restrict__ fcw,  const float* __restrict__ fcb,
               float* __restrict__ out)
{
    // arena: tile A h1 at [0],[BUFE]; h2 at [2B],[3B]; tile B same +4*BUFE
    __shared__ _Float16 arena[8 * BUFE];          // 32 KB
    __shared__ float hfin[BT][Hd];                // 8 KB

    const int tid  = threadIdx.x;
    const int lane = tid & 63;
    const int wave = tid >> 6;
    const int grp  = wave >> 2;            // 0 = layer1 waves, 1 = layer2 waves
    const int wg   = wave & 3;             // which 16 gate-cols this wave owns
    const int m    = lane & 15;            // A row (W row) AND B col (batch)
    const int quad = lane >> 4;            // k-chunk (A/B), row-group (C/D)
    const int col  = (wg << 4) + m;        // W row this lane loads (A-frag)
    const int gc   = (wg << 4) + (quad << 2); // C-frag: gate/h col base this lane owns
    const int b0   = blockIdx.x << 5;      // 32 batches per block (two 16-tiles)

    for (int idx = tid; idx < 8 * BUFE; idx += 512) arena[idx] = (_Float16)0.f;

    const float sRZ = -1.44269504f;        // -log2(e)
    const float sN  = -2.88539008f;        // -2*log2(e)

    // ---- persistent pre-scaled weight A-fragments, SHARED by both tiles ----
    half8 wx[2][3], wh[2][3];
    f32x4 brz0v, brz1v, binv, bhnv;

    if (grp == 0) {
        wx[0][0] = load8s(Wih0 + (      col) * Din + quad * 8, sRZ);
        wx[0][1] = load8s(Wih0 + ( 64 + col) * Din + quad * 8, sRZ);
        wx[0][2] = load8s(Wih0 + (128 + col) * Din + quad * 8, sN);
#pragma unroll
        for (int kb = 0; kb < 2; ++kb) {
            wh[kb][0] = load8s(Whh0 + (      col) * Hd + kb * 32 + quad * 8, sRZ);
            wh[kb][1] = load8s(Whh0 + ( 64 + col) * Hd + kb * 32 + quad * 8, sRZ);
            wh[kb][2] = load8s(Whh0 + (128 + col) * Hd + kb * 32 + quad * 8, sN);
        }
#pragma unroll
        for (int r = 0; r < 4; ++r) {
            brz0v[r] = sRZ * (bih0[gc + r] + bhh0[gc + r]);
            brz1v[r] = sRZ * (bih0[64 + gc + r] + bhh0[64 + gc + r]);
            binv[r]  = sN * bih0[128 + gc + r];
            bhnv[r]  = sN * bhh0[128 + gc + r];
        }
    } else {
#pragma unroll
        for (int kb = 0; kb < 2; ++kb) {
            wx[kb][0] = load8s(Wih1 + (      col) * Hd + kb * 32 + quad * 8, sRZ);
            wx[kb][1] = load8s(Wih1 + ( 64 + col) * Hd + kb * 32 + quad * 8, sRZ);
            wx[kb][2] = load8s(Wih1 + (128 + col) * Hd + kb * 32 + quad * 8, sN);
            wh[kb][0] = load8s(Whh1 + (      col) * Hd + kb * 32 + quad * 8, sRZ);
            wh[kb][1] = load8s(Whh1 + ( 64 + col) * Hd + kb * 32 + quad * 8, sRZ);
            wh[kb][2] = load8s(Whh1 + (128 + col) * Hd + kb * 32 + quad * 8, sN);
        }
#pragma unroll
        for (int r = 0; r < 4; ++r) {
            brz0v[r] = sRZ * (bih1[gc + r] + bhh1[gc + r]);
            brz1v[r] = sRZ * (bih1[64 + gc + r] + bhh1[64 + gc + r]);
            binv[r]  = sN * bih1[128 + gc + r];
            bhnv[r]  = sN * bhh1[128 + gc + r];
        }
    }

    const int rdoff = m * HS + quad * 8;        // B-frag read: batch m, k = quad*8..
    const int wroff = m * HS + gc;              // C write: row = batch m, cols gc..+3
    float hstA[4] = {0.f, 0.f, 0.f, 0.f};
    float hstB[4] = {0.f, 0.f, 0.f, 0.f};

    // ---- x direct from global (no LDS staging): 2-step-deep register prefetch.
    // Lane (quad,m) needs x[b0+m][t][quad*8 .. quad*8+7] = 2 float4. All 4 grp0
    // waves read identical addresses (L1/L2 absorbs the redundancy).
    const float* xgpA = x + (size_t)(b0 + m) * (Tlen * Din) + quad * 8;
    const float* xgpB = xgpA + (size_t)16 * (Tlen * Din);
    float4 xA0a, xA0b, xB0a, xB0b;   // parity-0 buffer (even steps)
    float4 xA1a, xA1b, xB1a, xB1b;   // parity-1 buffer (odd steps)
    if (grp == 0) {
        xA0a = *(const float4*)(xgpA);        xA0b = *(const float4*)(xgpA + 4);
        xB0a = *(const float4*)(xgpB);        xB0b = *(const float4*)(xgpB + 4);
        xA1a = *(const float4*)(xgpA + Din);  xA1b = *(const float4*)(xgpA + Din + 4);
        xB1a = *(const float4*)(xgpB + Din);  xB1b = *(const float4*)(xgpB + Din + 4);
    }
    __syncthreads();

// one recurrence step for BOTH tiles; RO/WO compile-time buffer offsets;
// xAa..xBb are the parity-(I&1) x register buffers (used now, then refilled
// with x[I+2] -> ~2 regions of latency slack for the global loads).
#define STEP(I, RO, WO, xAa, xAb, xBa, xBb)                                      \
  do {                                                                           \
    if (grp == 0) {                                                              \
      const _Float16* sA = arena + (RO) + rdoff;                                 \
      const _Float16* sB = sA + 4 * BUFE;                                        \
      half8 bhA0 = *(const half8*)sA;                                            \
      half8 bhA1 = *(const half8*)(sA + 32);                                     \
      half8 bhB0 = *(const half8*)sB;                                            \
      half8 bhB1 = *(const half8*)(sB + 32);                                     \
      half8 axA = cvt8(xAa, xAb);                                                \
      half8 axB = cvt8(xBa, xBb);                                                \
      { const int nx = ((I) + 2 < Tlen) ? (I) + 2 : Tlen - 1;                    \
        const float* pA = xgpA + (size_t)nx * Din;                               \
        const float* pB = xgpB + (size_t)nx * Din;                               \
        xAa = *(const float4*)pA; xAb = *(const float4*)(pA + 4);                \
        xBa = *(const float4*)pB; xBb = *(const float4*)(pB + 4); }              \
      f32x4 arhA = {0.f,0.f,0.f,0.f}, azhA = {0.f,0.f,0.f,0.f}, anhA = bhnv;     \
      f32x4 arhB = {0.f,0.f,0.f,0.f}, azhB = {0.f,0.f,0.f,0.f}, anhB = bhnv;     \
      arhA = MFMA(wh[0][0], bhA0, arhA); arhA = MFMA(wh[1][0], bhA1, arhA);      \
      arhB = MFMA(wh[0][0], bhB0, arhB); arhB = MFMA(wh[1][0], bhB1, arhB);      \
      azhA = MFMA(wh[0][1], bhA0, azhA); azhA = MFMA(wh[1][1], bhA1, azhA);      \
      azhB = MFMA(wh[0][1], bhB0, azhB); azhB = MFMA(wh[1][1], bhB1, azhB);      \
      anhA = MFMA(wh[0][2], bhA0, anhA); anhA = MFMA(wh[1][2], bhA1, anhA);      \
      anhB = MFMA(wh[0][2], bhB0, anhB); anhB = MFMA(wh[1][2], bhB1, anhB);      \
      f32x4 arxA = brz0v, azxA = brz1v, anxA = binv;                             \
      f32x4 arxB = brz0v, azxB = brz1v, anxB = binv;                             \
      arxA = MFMA(wx[0][0], axA, arxA);  arxB = MFMA(wx[0][0], axB, arxB);       \
      azxA = MFMA(wx[0][1], axA, azxA);  azxB = MFMA(wx[0][1], axB, azxB);       \
      anxA = MFMA(wx[0][2], axA, anxA);  anxB = MFMA(wx[0][2], axB, anxB);       \
      f32x4 grA = arxA + arhA, gzA = azxA + azhA;                                \
      f32x4 grB = arxB + arhB, gzB = azxB + azhB;                                \
      gate_update(grA, gzA, anxA, anhA, hstA, arena + (WO) + wroff, true);       \
      gate_update(grB, gzB, anxB, anhB, hstB,                                    \
                  arena + 4 * BUFE + (WO) + wroff, true);                        \
    } else {                                                                     \
      const _Float16* s1A = arena + (RO) + rdoff;            /* h1A[I-1] */      \
      const _Float16* s2A = s1A + 2 * BUFE;                  /* h2A[I-2] */      \
      const _Float16* s1B = s1A + 4 * BUFE;                                      \
      const _Float16* s2B = s1B + 2 * BUFE;                                      \
      half8 bxA0 = *(const half8*)s1A;                                           \
      half8 bxA1 = *(const half8*)(s1A + 32);                                    \
      half8 bhA0 = *(const half8*)s2A;                                           \
      half8 bhA1 = *(const half8*)(s2A + 32);                                    \
      half8 bxB0 = *(const half8*)s1B;                                           \
      half8 bxB1 = *(const half8*)(s1B + 32);                                    \
      half8 bhB0 = *(const half8*)s2B;                                           \
      half8 bhB1 = *(const half8*)(s2B + 32);                                    \
      f32x4 arxA = brz0v, azxA = brz1v, anxA = binv;                             \
      f32x4 arhA = {0.f,0.f,0.f,0.f}, azhA = {0.f,0.f,0.f,0.f}, anhA = bhnv;     \
      f32x4 arxB = brz0v, azxB = brz1v, anxB = binv;                             \
      f32x4 arhB = {0.f,0.f,0.f,0.f}, azhB = {0.f,0.f,0.f,0.f}, anhB = bhnv;     \
      arxA = MFMA(wx[0][0], bxA0, arxA); arxA = MFMA(wx[1][0], bxA1, arxA);      \
      arxB = MFMA(wx[0][0], bxB0, arxB); arxB = MFMA(wx[1][0], bxB1, arxB);      \
      azxA = MFMA(wx[0][1], bxA0, azxA); azxA = MFMA(wx[1][1], bxA1, azxA);      \
      azxB = MFMA(wx[0][1], bxB0, azxB); azxB = MFMA(wx[1][1], bxB1, azxB);      \
      anxA = MFMA(wx[0][2], bxA0, anxA); anxA = MFMA(wx[1][2], bxA1, anxA);      \
      anxB = MFMA(wx[0][2], bxB0, anxB); anxB = MFMA(wx[1][2], bxB1, anxB);      \
      arhA = MFMA(wh[0][0], bhA0, arhA); arhA = MFMA(wh[1][0], bhA1, arhA);      \
      arhB = MFMA(wh[0][0], bhB0, arhB); arhB = MFMA(wh[1][0], bhB1, arhB);      \
      azhA = MFMA(wh[0][1], bhA0, azhA); azhA = MFMA(wh[1][1], bhA1, azhA);      \
      azhB = MFMA(wh[0][1], bhB0, azhB); azhB = MFMA(wh[1][1], bhB1, azhB);      \
      anhA = MFMA(wh[0][2], bhA0, anhA); anhA = MFMA(wh[1][2], bhA1, anhA);      \
      anhB = MFMA(wh[0][2], bhB0, anhB); anhB = MFMA(wh[1][2], bhB1, anhB);      \
      f32x4 grA = arxA + arhA, gzA = azxA + azhA;                                \
      f32x4 grB = arxB + arhB, gzB = azxB + azhB;                                \
      gate_update(grA, gzA, anxA, anhA, hstA,                                    \
                  arena + 2 * BUFE + (WO) + wroff, true);                        \
      gate_update(grB, gzB, anxB, anhB, hstB,                                    \
                  arena + 6 * BUFE + (WO) + wroff, true);                        \
    }                                                                            \
    __syncthreads();                                                             \
  } while (0)

    // ---------- peel i = 0 : L1 only; h1[-1]=0 so h-side MFMAs are skipped ----------
    if (grp == 0) {
        half8 axA = cvt8(xA0a, xA0b);
        half8 axB = cvt8(xB0a, xB0b);
        {   // refill parity-0 bufs with x[2]
            const float* pA = xgpA + 2 * Din;
            const float* pB = xgpB + 2 * Din;
            xA0a = *(const float4*)pA; xA0b = *(const float4*)(pA + 4);
            xB0a = *(const float4*)pB; xB0b = *(const float4*)(pB + 4);
        }
        f32x4 grA = brz0v, gzA = brz1v, anxA = binv, anhA = bhnv;
        grA  = MFMA(wx[0][0], axA, grA);
        gzA  = MFMA(wx[0][1], axA, gzA);
        anxA = MFMA(wx[0][2], axA, anxA);
        gate_update(grA, gzA, anxA, anhA, hstA, arena + 0 + wroff, true);
        f32x4 grB = brz0v, gzB = brz1v, anxB = binv, anhB = bhnv;
        grB  = MFMA(wx[0][0], axB, grB);
        gzB  = MFMA(wx[0][1], axB, gzB);
        anxB = MFMA(wx[0][2], axB, anxB);
        gate_update(grB, gzB, anxB, anhB, hstB, arena + 4 * BUFE + wroff, true);
    }
    __syncthreads();

    // ---------- main: steps 1..511; odd steps read buf0/write buf1, even reverse ----
    for (int i = 1; i + 1 < Tlen; i += 2) {
        STEP(i,     0,    BUFE, xA1a, xA1b, xB1a, xB1b);   // odd step
        STEP(i + 1, BUFE, 0,    xA0a, xA0b, xB0a, xB0b);   // even step
    }
    STEP(Tlen - 1, 0, BUFE, xA1a, xA1b, xB1a, xB1b);       // step 511

    // ---------- peel i = T : L2 only, computes h2[T-1], no LDS writeback ----------
    if (grp == 1) {
#pragma unroll
        for (int t = 0; t < 2; ++t) {
            const _Float16* s1 = arena + t * 4 * BUFE + BUFE + rdoff;  // h1[511]
            const _Float16* s2 = s1 + 2 * BUFE;                        // h2[510]
            half8 bx0 = *(const half8*)s1;
            half8 bx1 = *(const half8*)(s1 + 32);
            half8 bh0 = *(const half8*)s2;
            half8 bh1 = *(const half8*)(s2 + 32);
            f32x4 arx = brz0v, azx = brz1v, anx = binv;
            f32x4 arh = {0.f,0.f,0.f,0.f}, azh = {0.f,0.f,0.f,0.f}, anh = bhnv;
            arx = MFMA(wx[0][0], bx0, arx); arx = MFMA(wx[1][0], bx1, arx);
            azx = MFMA(wx[0][1], bx0, azx); azx = MFMA(wx[1][1], bx1, azx);
            anx = MFMA(wx[0][2], bx0, anx); anx = MFMA(wx[1][2], bx1, anx);
            arh = MFMA(wh[0][0], bh0, arh); arh = MFMA(wh[1][0], bh1, arh);
            azh = MFMA(wh[0][1], bh0, azh); azh = MFMA(wh[1][1], bh1, azh);
            anh = MFMA(wh[0][2], bh0, anh); anh = MFMA(wh[1][2], bh1, anh);
            f32x4 gr = arx + arh, gz = azx + azh;
            float* hs = t ? hstB : hstA;
            gate_update(gr, gz, anx, anh, hs, nullptr, false);
            f32x4 fv;
#pragma unroll
            for (int r = 0; r < 4; ++r) fv[r] = hs[r];
            *(f32x4*)(&hfin[t * 16 + m][gc]) = fv;    // batch, cols gc..gc+3
        }
    }
    __syncthreads();
    if (tid < BT) {                                // FC head (32 batches)
        float acc = fcb[0];
        for (int c = 0; c < Hd; ++c) acc += hfin[tid][c] * fcw[c];
        out[b0 + tid] = acc;
    }
#undef STEP
}

extern "C" void kernel_launch(void* const* d_in, const int* in_sizes, int n_in,
                              void* d_out, int out_size, void* d_ws, size_t ws_size,
                              hipStream_t stream) {
    gru_fused<<<dim3(Bsz / BT), dim3(512), 0, stream>>>(
        (const float*)d_in[0],
        (const float*)d_in[1], (const float*)d_in[2],
        (const float*)d_in[3], (const float*)d_in[4],
        (const float*)d_in[5], (const float*)d_in[6],
        (const float*)d_in[7], (const float*)d_in[8],
        (const float*)d_in[9], (const float*)d_in[10],
        (float*)d_out);
}